// Round 6
// baseline (6914.949 us; speedup 1.0000x reference)
//
#include <hip/hip_runtime.h>

// LSTM surrogate: B=256, T=512, D=256, U=512, O=64.
// R6 = R5 resubmitted verbatim (R5 died to an infra flake before the bench ran).
// R5 = R4 + (a) release flag-store / single acquire after poll (model-correct
// cross-XCD ordering, once per step), (b) XCD-affine group mapping (perf).
// 16 batch-groups x 16 rows, 32 unit-groups -> grid 512, 2 blocks/CU.

#define Bb 256
#define Tt 512
#define Dd 256
#define Uu 512
#define Oo 64

typedef short bs8 __attribute__((ext_vector_type(8)));      // 8 bf16 (bits)
typedef float f32x4 __attribute__((ext_vector_type(4)));

__device__ __forceinline__ unsigned short f2bf(float f) {
  unsigned u = __float_as_uint(f);
  u += 0x7fffu + ((u >> 16) & 1u);                          // RNE
  return (unsigned short)(u >> 16);
}
__device__ __forceinline__ float bf2f(unsigned short s) {
  return __uint_as_float(((unsigned)s) << 16);
}
__device__ __forceinline__ float sigm(float v) { return 1.0f / (1.0f + __expf(-v)); }
__device__ __forceinline__ float tanhfast(float v) { return 2.0f / (1.0f + __expf(-2.0f * v)) - 1.0f; }

// z LDS: [16 rows][768 k] bf16, row stride 1536 B. XOR swizzle on 16B granules.
__device__ __forceinline__ int zbyte(int row, int k) {
  return (row * 1536 + k * 2) ^ ((row & 7) << 4);
}

__global__ void rnn_init_bar(unsigned* bar) {
  __hip_atomic_store(&bar[threadIdx.x], 0u, __ATOMIC_RELAXED, __HIP_MEMORY_SCOPE_AGENT);
}

__launch_bounds__(256, 2)
__global__ void rnn_lstm_kernel(const float* __restrict__ x, const float* __restrict__ Wx,
                                const float* __restrict__ Wh, const float* __restrict__ bias,
                                const float* __restrict__ Wd, const float* __restrict__ bd,
                                float* __restrict__ out, unsigned short* hbuf, unsigned* bar) {
  __shared__ __align__(16) char zs[16 * 768 * 2];   // 24576 B
  __shared__ float gates[4][16][17];                // [gate][row][unit], pad
  __shared__ float wdl[512][2];                     // Wd slice for this block's 2 out cols
  __shared__ float ypart[16][2][16];                // [row][oc][usec]

  const int tid = threadIdx.x;
  const int lane = tid & 63;
  const int wid = tid >> 6;                         // wave 0..3 == gate id
  const int bid = blockIdx.x;
  // XCD-affine grouping (perf heuristic only; correctness rests on acq/rel):
  // group g's 32 blocks all have bid%8 == g%8 -> same XCD under %8 dispatch.
  const int bg = (bid & 7) | ((bid >> 8) << 3);     // 0..15
  const int ug = (bid >> 3) & 31;                   // 0..31
  const int b_base = bg * 16;
  const int u_base = ug * 16;
  const int oc0 = ug * 2;

  unsigned* fl = bar + bg * 32;  // 32 per-block flags, one 128B line per group

  // ---- load weight slice as B-fragments (once): wave w = gate w ----
  // B-frag (16x16x32): col = lane&15, k = (lane>>4)*8 + e (m97-verified convention)
  bs8 breg[24];
  {
    const int gc = wid * 512 + u_base + (lane & 15); // gate-major column in [.,2048]
    const int kfr = (lane >> 4) * 8;
#pragma unroll
    for (int ks = 0; ks < 24; ++ks) {
      bs8 bb;
#pragma unroll
      for (int e = 0; e < 8; ++e) {
        int kg = ks * 32 + kfr + e;
        float w = (kg < 256) ? Wx[(size_t)kg * 2048 + gc]
                             : Wh[(size_t)(kg - 256) * 2048 + gc];
        bb[e] = (short)f2bf(w);
      }
      breg[ks] = bb;
    }
  }

  // pointwise ownership (tid<128): row = tid&15, up = tid>>4 (0..7), units up*2+{0,1}
  const int prow = tid & 15;
  const int usec = tid >> 4;                        // 0..15 (y-decode sections of 32 units)
  const int up = usec & 7;
  float bi[2], bff[2], bgg[2], boo[2];
  if (tid < 128) {
#pragma unroll
    for (int j = 0; j < 2; ++j) {
      int ugl = u_base + up * 2 + j;
      bi[j]  = bias[0 * 512 + ugl];
      bff[j] = bias[1 * 512 + ugl];
      bgg[j] = bias[2 * 512 + ugl];
      boo[j] = bias[3 * 512 + ugl];
    }
  }
  float cst[2] = {0.f, 0.f};

  union U16 { unsigned long long q[2]; bs8 v; };

  // ---- prologue: Wd slice to LDS, stage x_0, zero h-region ----
#pragma unroll
  for (int i = 0; i < 4; ++i) {
    int c = tid + i * 256;        // 0..1023
    int u = c >> 1, oc = c & 1;
    wdl[u][oc] = Wd[(size_t)u * Oo + oc0 + oc];
  }
  {
    int row = tid >> 4;
    int d0 = (tid & 15) * 16;
    const float* xp = x + ((size_t)(b_base + row) * Tt + 0) * Dd + d0;
    float4 v0 = *(const float4*)xp;
    float4 v1 = *(const float4*)(xp + 4);
    float4 v2 = *(const float4*)(xp + 8);
    float4 v3 = *(const float4*)(xp + 12);
    bs8 p0, p1;
    p0[0] = (short)f2bf(v0.x); p0[1] = (short)f2bf(v0.y);
    p0[2] = (short)f2bf(v0.z); p0[3] = (short)f2bf(v0.w);
    p0[4] = (short)f2bf(v1.x); p0[5] = (short)f2bf(v1.y);
    p0[6] = (short)f2bf(v1.z); p0[7] = (short)f2bf(v1.w);
    p1[0] = (short)f2bf(v2.x); p1[1] = (short)f2bf(v2.y);
    p1[2] = (short)f2bf(v2.z); p1[3] = (short)f2bf(v2.w);
    p1[4] = (short)f2bf(v3.x); p1[5] = (short)f2bf(v3.y);
    p1[6] = (short)f2bf(v3.z); p1[7] = (short)f2bf(v3.w);
    *(bs8*)(zs + zbyte(row, d0)) = p0;
    *(bs8*)(zs + zbyte(row, d0 + 8)) = p1;
  }
#pragma unroll
  for (int i = 0; i < 4; ++i) {
    int c = tid + i * 256;        // 0..1023 chunks of 8
    int row = c >> 6;
    int u0 = (c & 63) * 8;
    bs8 zz = {0, 0, 0, 0, 0, 0, 0, 0};
    *(bs8*)(zs + zbyte(row, 256 + u0)) = zz;
  }
  __syncthreads();

  for (int t = 0; t < Tt; ++t) {
    // ---- gates MFMA: each wave computes its gate's [16 rows x 16 units], K=768 ----
    f32x4 acc0 = {0, 0, 0, 0}, acc1 = {0, 0, 0, 0};
    {
      const int arow = lane & 15;
      const int akf = (lane >> 4) * 8;
#pragma unroll
      for (int ks = 0; ks < 24; ks += 2) {
        bs8 av0 = *(const bs8*)(zs + zbyte(arow, ks * 32 + akf));
        bs8 av1 = *(const bs8*)(zs + zbyte(arow, (ks + 1) * 32 + akf));
        acc0 = __builtin_amdgcn_mfma_f32_16x16x32_bf16(av0, breg[ks], acc0, 0, 0, 0);
        acc1 = __builtin_amdgcn_mfma_f32_16x16x32_bf16(av1, breg[ks + 1], acc1, 0, 0, 0);
      }
      acc0 += acc1;
    }
    // C/D (HW-verified): col = lane&15, row = (lane>>4)*4 + reg
    {
      const int u16 = lane & 15;
      const int rb = (lane >> 4) * 4;
#pragma unroll
      for (int j = 0; j < 4; ++j) gates[wid][rb + j][u16] = acc0[j];
    }
    __syncthreads();

    // ---- pointwise LSTM cell (tid<128); h published bf16 (relaxed agent) ----
    if (tid < 128) {
      unsigned hpack = 0;
#pragma unroll
      for (int j = 0; j < 2; ++j) {
        int u = up * 2 + j;
        float gi = gates[0][prow][u] + bi[j];
        float gf = gates[1][prow][u] + bff[j];
        float gg = gates[2][prow][u] + bgg[j];
        float go = gates[3][prow][u] + boo[j];
        float iv = sigm(gi), fv = sigm(gf), gv = tanhfast(gg), ov = sigm(go);
        float cn = fv * cst[j] + iv * gv;
        cst[j] = cn;
        float hv = ov * tanhfast(cn);
        hpack |= ((unsigned)f2bf(hv)) << (16 * j);
      }
      unsigned* hp = (unsigned*)(hbuf + (size_t)(t & 1) * Bb * Uu +
                                 (size_t)(b_base + prow) * Uu + u_base + up * 2);
      __hip_atomic_store(hp, hpack, __ATOMIC_RELAXED, __HIP_MEMORY_SCOPE_AGENT);
    }
    // all waves drain their h-stores at this barrier; the RELEASE below then
    // publishes them (agent-release emits the required L2 writeback on gfx950).
    __syncthreads();
    if (tid == 0)
      __hip_atomic_store(&fl[ug], (unsigned)(t + 1), __ATOMIC_RELEASE, __HIP_MEMORY_SCOPE_AGENT);

    // ---- barrier window: stage x_{t+1} (x-region of zs is dead) ----
    if (t + 1 < Tt) {
      int row = tid >> 4;
      int d0 = (tid & 15) * 16;
      const float* xp = x + ((size_t)(b_base + row) * Tt + (t + 1)) * Dd + d0;
      float4 v0 = *(const float4*)xp;
      float4 v1 = *(const float4*)(xp + 4);
      float4 v2 = *(const float4*)(xp + 8);
      float4 v3 = *(const float4*)(xp + 12);
      bs8 p0, p1;
      p0[0] = (short)f2bf(v0.x); p0[1] = (short)f2bf(v0.y);
      p0[2] = (short)f2bf(v0.z); p0[3] = (short)f2bf(v0.w);
      p0[4] = (short)f2bf(v1.x); p0[5] = (short)f2bf(v1.y);
      p0[6] = (short)f2bf(v1.z); p0[7] = (short)f2bf(v1.w);
      p1[0] = (short)f2bf(v2.x); p1[1] = (short)f2bf(v2.y);
      p1[2] = (short)f2bf(v2.z); p1[3] = (short)f2bf(v2.w);
      p1[4] = (short)f2bf(v3.x); p1[5] = (short)f2bf(v3.y);
      p1[6] = (short)f2bf(v3.z); p1[7] = (short)f2bf(v3.w);
      *(bs8*)(zs + zbyte(row, d0)) = p0;
      *(bs8*)(zs + zbyte(row, d0 + 8)) = p1;
    }

    // ---- barrier window: y_{t-1} partials from LDS h copy ----
    if (t > 0) {
      float s0 = 0.f, s1 = 0.f;
#pragma unroll
      for (int c8 = 0; c8 < 4; ++c8) {
        int k = 256 + usec * 32 + c8 * 8;
        bs8 hv = *(const bs8*)(zs + zbyte(prow, k));
#pragma unroll
        for (int e = 0; e < 8; ++e) {
          float hf = bf2f((unsigned short)hv[e]);
          int u = usec * 32 + c8 * 8 + e;
          s0 += hf * wdl[u][0];
          s1 += hf * wdl[u][1];
        }
      }
      ypart[prow][0][usec] = s0;
      ypart[prow][1][usec] = s1;
    }
    __syncthreads();
    // y reduce on wave0, poll on wave1 (parallel)
    if (t > 0 && tid < 32) {
      int b = tid >> 1, oc = tid & 1;
      float s = bd[oc0 + oc];
#pragma unroll
      for (int q = 0; q < 16; ++q) s += ypart[b][oc][q];
      out[((size_t)(b_base + b) * Tt + (t - 1)) * Oo + oc0 + oc] = s;
    }
    if (wid == 1) {
      unsigned v;
      do {
        v = __hip_atomic_load(&fl[lane & 31], __ATOMIC_RELAXED, __HIP_MEMORY_SCOPE_AGENT);
      } while (__any((int)(v < (unsigned)(t + 1))));
      // ONE acquire edge per step: synchronizes-with all 32 release flag-stores,
      // invalidates stale L1/L2 so the h loads below read fresh data from L3.
      unsigned va = __hip_atomic_load(&fl[lane & 31], __ATOMIC_ACQUIRE, __HIP_MEMORY_SCOPE_AGENT);
      asm volatile("" :: "v"(va));
    }
    __builtin_amdgcn_sched_barrier(0);
    __syncthreads();

    // ---- stage h_t from hbuf[t&1] ----
    {
      const unsigned short* hsrc = hbuf + (size_t)(t & 1) * Bb * Uu;
#pragma unroll
      for (int i = 0; i < 4; ++i) {
        int c = tid + i * 256;
        int row = c >> 6;
        int u0 = (c & 63) * 8;
        const unsigned long long* p =
            (const unsigned long long*)(hsrc + (size_t)(b_base + row) * Uu + u0);
        U16 uu;
        uu.q[0] = __hip_atomic_load(p, __ATOMIC_RELAXED, __HIP_MEMORY_SCOPE_AGENT);
        uu.q[1] = __hip_atomic_load(p + 1, __ATOMIC_RELAXED, __HIP_MEMORY_SCOPE_AGENT);
        *(bs8*)(zs + zbyte(row, 256 + u0)) = uu.v;
      }
    }
    __syncthreads();
  }

  // ---- epilogue: y_{T-1} (h_{T-1} staged by final iteration) ----
  {
    float s0 = 0.f, s1 = 0.f;
#pragma unroll
    for (int c8 = 0; c8 < 4; ++c8) {
      int k = 256 + usec * 32 + c8 * 8;
      bs8 hv = *(const bs8*)(zs + zbyte(prow, k));
#pragma unroll
      for (int e = 0; e < 8; ++e) {
        float hf = bf2f((unsigned short)hv[e]);
        int u = usec * 32 + c8 * 8 + e;
        s0 += hf * wdl[u][0];
        s1 += hf * wdl[u][1];
      }
    }
    ypart[prow][0][usec] = s0;
    ypart[prow][1][usec] = s1;
    __syncthreads();
    if (tid < 32) {
      int b = tid >> 1, oc = tid & 1;
      float s = bd[oc0 + oc];
#pragma unroll
      for (int q = 0; q < 16; ++q) s += ypart[b][oc][q];
      out[((size_t)(b_base + b) * Tt + (Tt - 1)) * Oo + oc0 + oc] = s;
    }
  }
}

extern "C" void kernel_launch(void* const* d_in, const int* in_sizes, int n_in,
                              void* d_out, int out_size, void* d_ws, size_t ws_size,
                              hipStream_t stream) {
  const float* x  = (const float*)d_in[0];
  const float* Wx = (const float*)d_in[1];
  const float* Wh = (const float*)d_in[2];
  const float* bs = (const float*)d_in[3];
  const float* Wd = (const float*)d_in[4];
  const float* bd = (const float*)d_in[5];
  float* out = (float*)d_out;

  unsigned short* hbuf = (unsigned short*)d_ws;                       // 2*256*512 bf16 = 512 KiB
  unsigned* bar = (unsigned*)((char*)d_ws + (size_t)2 * Bb * Uu * 2); // 16 groups * 32 flags

  rnn_init_bar<<<1, 512, 0, stream>>>(bar);
  rnn_lstm_kernel<<<dim3(512), dim3(256), 0, stream>>>(x, Wx, Wh, bs, Wd, bd, out, hbuf, bar);
}

// Round 8
// 2408.712 us; speedup vs baseline: 2.8708x; 2.8708x over previous
//
#include <hip/hip_runtime.h>

// LSTM surrogate: B=256, T=512, D=256, U=512, O=64.
// R8 = R7 resubmitted verbatim (R7 died to the same pre-bench infra flake as R5;
// the R5->R6 precedent shows byte-identical resubmission is the correct move).
// R7 = R6 with cache-maintenance-free cross-XCD ordering:
//   h published via global_atomic_swap_x2 (sc0: executes+acks at L3) ->
//   syncthreads vmcnt-drain guarantees L3 visibility BEFORE flag store.
//   No RELEASE (buffer_wbl2) / no ACQUIRE (buffer_inv) per step.
// 16 batch-groups x 16 rows, 32 unit-groups -> grid 512, 2 blocks/CU.

#define Bb 256
#define Tt 512
#define Dd 256
#define Uu 512
#define Oo 64

typedef short bs8 __attribute__((ext_vector_type(8)));      // 8 bf16 (bits)
typedef float f32x4 __attribute__((ext_vector_type(4)));

__device__ __forceinline__ unsigned short f2bf(float f) {
  unsigned u = __float_as_uint(f);
  u += 0x7fffu + ((u >> 16) & 1u);                          // RNE
  return (unsigned short)(u >> 16);
}
__device__ __forceinline__ float bf2f(unsigned short s) {
  return __uint_as_float(((unsigned)s) << 16);
}
__device__ __forceinline__ float sigm(float v) { return 1.0f / (1.0f + __expf(-v)); }
__device__ __forceinline__ float tanhfast(float v) { return 2.0f / (1.0f + __expf(-2.0f * v)) - 1.0f; }

// z LDS: [16 rows][768 k] bf16, row stride 1536 B. XOR swizzle on 16B granules.
__device__ __forceinline__ int zbyte(int row, int k) {
  return (row * 1536 + k * 2) ^ ((row & 7) << 4);
}

__global__ void rnn_init_bar(unsigned* bar) {
  __hip_atomic_store(&bar[threadIdx.x], 0u, __ATOMIC_RELAXED, __HIP_MEMORY_SCOPE_AGENT);
}

__launch_bounds__(256, 2)
__global__ void rnn_lstm_kernel(const float* __restrict__ x, const float* __restrict__ Wx,
                                const float* __restrict__ Wh, const float* __restrict__ bias,
                                const float* __restrict__ Wd, const float* __restrict__ bd,
                                float* __restrict__ out, unsigned short* hbuf, unsigned* bar) {
  __shared__ __align__(16) char zs[16 * 768 * 2];   // 24576 B
  __shared__ float gates[4][16][17];                // [gate][row][unit], pad
  __shared__ float wdl[512][2];                     // Wd slice for this block's 2 out cols
  __shared__ float ypart[16][2][16];                // [row][oc][usec]

  const int tid = threadIdx.x;
  const int lane = tid & 63;
  const int wid = tid >> 6;                         // wave 0..3 == gate id
  const int bid = blockIdx.x;
  // XCD-affine grouping (perf heuristic only; correctness rests on swap-at-L3):
  const int bg = (bid & 7) | ((bid >> 8) << 3);     // 0..15
  const int ug = (bid >> 3) & 31;                   // 0..31
  const int b_base = bg * 16;
  const int u_base = ug * 16;
  const int oc0 = ug * 2;

  unsigned* fl = bar + bg * 32;  // 32 per-block flags, one 128B line per group

  // ---- load weight slice as B-fragments (once): wave w = gate w ----
  // B-frag (16x16x32): col = lane&15, k = (lane>>4)*8 + e (m97-verified convention)
  bs8 breg[24];
  {
    const int gc = wid * 512 + u_base + (lane & 15); // gate-major column in [.,2048]
    const int kfr = (lane >> 4) * 8;
#pragma unroll
    for (int ks = 0; ks < 24; ++ks) {
      bs8 bb;
#pragma unroll
      for (int e = 0; e < 8; ++e) {
        int kg = ks * 32 + kfr + e;
        float w = (kg < 256) ? Wx[(size_t)kg * 2048 + gc]
                             : Wh[(size_t)(kg - 256) * 2048 + gc];
        bb[e] = (short)f2bf(w);
      }
      breg[ks] = bb;
    }
  }

  // pointwise ownership (tid<64): row = tid&15, us4 = tid>>4 (0..3), units us4*4+{0..3}
  // (4 units/thread -> one 8B atomic swap_x2 per thread publishes h at L3)
  const int prow = tid & 15;
  const int usec = tid >> 4;                        // 0..15 (y-decode sections of 32 units)
  const int us4 = usec & 3;
  float bi[4], bff[4], bgg[4], boo[4];
  if (tid < 64) {
#pragma unroll
    for (int j = 0; j < 4; ++j) {
      int ugl = u_base + us4 * 4 + j;
      bi[j]  = bias[0 * 512 + ugl];
      bff[j] = bias[1 * 512 + ugl];
      bgg[j] = bias[2 * 512 + ugl];
      boo[j] = bias[3 * 512 + ugl];
    }
  }
  float cst[4] = {0.f, 0.f, 0.f, 0.f};

  union U16 { unsigned long long q[2]; bs8 v; };

  // ---- prologue: Wd slice to LDS, stage x_0, zero h-region ----
#pragma unroll
  for (int i = 0; i < 4; ++i) {
    int c = tid + i * 256;        // 0..1023
    int u = c >> 1, oc = c & 1;
    wdl[u][oc] = Wd[(size_t)u * Oo + oc0 + oc];
  }
  {
    int row = tid >> 4;
    int d0 = (tid & 15) * 16;
    const float* xp = x + ((size_t)(b_base + row) * Tt + 0) * Dd + d0;
    float4 v0 = *(const float4*)xp;
    float4 v1 = *(const float4*)(xp + 4);
    float4 v2 = *(const float4*)(xp + 8);
    float4 v3 = *(const float4*)(xp + 12);
    bs8 p0, p1;
    p0[0] = (short)f2bf(v0.x); p0[1] = (short)f2bf(v0.y);
    p0[2] = (short)f2bf(v0.z); p0[3] = (short)f2bf(v0.w);
    p0[4] = (short)f2bf(v1.x); p0[5] = (short)f2bf(v1.y);
    p0[6] = (short)f2bf(v1.z); p0[7] = (short)f2bf(v1.w);
    p1[0] = (short)f2bf(v2.x); p1[1] = (short)f2bf(v2.y);
    p1[2] = (short)f2bf(v2.z); p1[3] = (short)f2bf(v2.w);
    p1[4] = (short)f2bf(v3.x); p1[5] = (short)f2bf(v3.y);
    p1[6] = (short)f2bf(v3.z); p1[7] = (short)f2bf(v3.w);
    *(bs8*)(zs + zbyte(row, d0)) = p0;
    *(bs8*)(zs + zbyte(row, d0 + 8)) = p1;
  }
#pragma unroll
  for (int i = 0; i < 4; ++i) {
    int c = tid + i * 256;        // 0..1023 chunks of 8
    int row = c >> 6;
    int u0 = (c & 63) * 8;
    bs8 zz = {0, 0, 0, 0, 0, 0, 0, 0};
    *(bs8*)(zs + zbyte(row, 256 + u0)) = zz;
  }
  __syncthreads();

  for (int t = 0; t < Tt; ++t) {
    // ---- gates MFMA: each wave computes its gate's [16 rows x 16 units], K=768 ----
    f32x4 acc0 = {0, 0, 0, 0}, acc1 = {0, 0, 0, 0};
    {
      const int arow = lane & 15;
      const int akf = (lane >> 4) * 8;
#pragma unroll
      for (int ks = 0; ks < 24; ks += 2) {
        bs8 av0 = *(const bs8*)(zs + zbyte(arow, ks * 32 + akf));
        bs8 av1 = *(const bs8*)(zs + zbyte(arow, (ks + 1) * 32 + akf));
        acc0 = __builtin_amdgcn_mfma_f32_16x16x32_bf16(av0, breg[ks], acc0, 0, 0, 0);
        acc1 = __builtin_amdgcn_mfma_f32_16x16x32_bf16(av1, breg[ks + 1], acc1, 0, 0, 0);
      }
      acc0 += acc1;
    }
    // C/D (HW-verified): col = lane&15, row = (lane>>4)*4 + reg
    {
      const int u16 = lane & 15;
      const int rb = (lane >> 4) * 4;
#pragma unroll
      for (int j = 0; j < 4; ++j) gates[wid][rb + j][u16] = acc0[j];
    }
    __syncthreads();

    // ---- pointwise LSTM cell (tid<64); h published via atomic swap_x2 ----
    // swap executes at L3 (returns old, sc0): its vmcnt-ack == L3 visibility.
    if (tid < 64) {
      unsigned long long hpack = 0ull;
#pragma unroll
      for (int j = 0; j < 4; ++j) {
        int u = us4 * 4 + j;
        float gi = gates[0][prow][u] + bi[j];
        float gf = gates[1][prow][u] + bff[j];
        float gg = gates[2][prow][u] + bgg[j];
        float go = gates[3][prow][u] + boo[j];
        float iv = sigm(gi), fv = sigm(gf), gv = tanhfast(gg), ov = sigm(go);
        float cn = fv * cst[j] + iv * gv;
        cst[j] = cn;
        float hv = ov * tanhfast(cn);
        hpack |= ((unsigned long long)f2bf(hv)) << (16 * j);
      }
      unsigned long long* hp =
          (unsigned long long*)(hbuf + (size_t)(t & 1) * Bb * Uu +
                                (size_t)(b_base + prow) * Uu + u_base + us4 * 4);
      unsigned long long old = __hip_atomic_exchange(hp, hpack, __ATOMIC_RELAXED,
                                                     __HIP_MEMORY_SCOPE_AGENT);
      asm volatile("" :: "v"(old));   // keep the returning (sc0) form
    }
    // barrier drains each wave's vmcnt: all h-swaps have EXECUTED AT L3 here.
    __syncthreads();
    if (tid == 0) {
      unsigned oldf = __hip_atomic_exchange(&fl[ug], (unsigned)(t + 1),
                                            __ATOMIC_RELAXED, __HIP_MEMORY_SCOPE_AGENT);
      asm volatile("" :: "v"(oldf));
    }

    // ---- barrier window: stage x_{t+1} (x-region of zs is dead) ----
    if (t + 1 < Tt) {
      int row = tid >> 4;
      int d0 = (tid & 15) * 16;
      const float* xp = x + ((size_t)(b_base + row) * Tt + (t + 1)) * Dd + d0;
      float4 v0 = *(const float4*)xp;
      float4 v1 = *(const float4*)(xp + 4);
      float4 v2 = *(const float4*)(xp + 8);
      float4 v3 = *(const float4*)(xp + 12);
      bs8 p0, p1;
      p0[0] = (short)f2bf(v0.x); p0[1] = (short)f2bf(v0.y);
      p0[2] = (short)f2bf(v0.z); p0[3] = (short)f2bf(v0.w);
      p0[4] = (short)f2bf(v1.x); p0[5] = (short)f2bf(v1.y);
      p0[6] = (short)f2bf(v1.z); p0[7] = (short)f2bf(v1.w);
      p1[0] = (short)f2bf(v2.x); p1[1] = (short)f2bf(v2.y);
      p1[2] = (short)f2bf(v2.z); p1[3] = (short)f2bf(v2.w);
      p1[4] = (short)f2bf(v3.x); p1[5] = (short)f2bf(v3.y);
      p1[6] = (short)f2bf(v3.z); p1[7] = (short)f2bf(v3.w);
      *(bs8*)(zs + zbyte(row, d0)) = p0;
      *(bs8*)(zs + zbyte(row, d0 + 8)) = p1;
    }

    // ---- barrier window: y_{t-1} partials from LDS h copy ----
    if (t > 0) {
      float s0 = 0.f, s1 = 0.f;
#pragma unroll
      for (int c8 = 0; c8 < 4; ++c8) {
        int k = 256 + usec * 32 + c8 * 8;
        bs8 hv = *(const bs8*)(zs + zbyte(prow, k));
#pragma unroll
        for (int e = 0; e < 8; ++e) {
          float hf = bf2f((unsigned short)hv[e]);
          int u = usec * 32 + c8 * 8 + e;
          s0 += hf * wdl[u][0];
          s1 += hf * wdl[u][1];
        }
      }
      ypart[prow][0][usec] = s0;
      ypart[prow][1][usec] = s1;
    }
    __syncthreads();
    // y reduce on wave0, poll on wave1 (parallel)
    if (t > 0 && tid < 32) {
      int b = tid >> 1, oc = tid & 1;
      float s = bd[oc0 + oc];
#pragma unroll
      for (int q = 0; q < 16; ++q) s += ypart[b][oc][q];
      out[((size_t)(b_base + b) * Tt + (t - 1)) * Oo + oc0 + oc] = s;
    }
    if (wid == 1) {
      unsigned v;
      do {
        v = __hip_atomic_load(&fl[lane & 31], __ATOMIC_RELAXED, __HIP_MEMORY_SCOPE_AGENT);
      } while (__any((int)(v < (unsigned)(t + 1))));
      // no acquire needed: flag seen => producers' swaps already executed at L3,
      // and the sc1 h-loads below read L3 directly (bypass stale L1/L2).
    }
    __builtin_amdgcn_sched_barrier(0);
    __syncthreads();

    // ---- stage h_t from hbuf[t&1] ----
    {
      const unsigned short* hsrc = hbuf + (size_t)(t & 1) * Bb * Uu;
#pragma unroll
      for (int i = 0; i < 4; ++i) {
        int c = tid + i * 256;
        int row = c >> 6;
        int u0 = (c & 63) * 8;
        const unsigned long long* p =
            (const unsigned long long*)(hsrc + (size_t)(b_base + row) * Uu + u0);
        U16 uu;
        uu.q[0] = __hip_atomic_load(p, __ATOMIC_RELAXED, __HIP_MEMORY_SCOPE_AGENT);
        uu.q[1] = __hip_atomic_load(p + 1, __ATOMIC_RELAXED, __HIP_MEMORY_SCOPE_AGENT);
        *(bs8*)(zs + zbyte(row, 256 + u0)) = uu.v;
      }
    }
    __syncthreads();
  }

  // ---- epilogue: y_{T-1} (h_{T-1} staged by final iteration) ----
  {
    float s0 = 0.f, s1 = 0.f;
#pragma unroll
    for (int c8 = 0; c8 < 4; ++c8) {
      int k = 256 + usec * 32 + c8 * 8;
      bs8 hv = *(const bs8*)(zs + zbyte(prow, k));
#pragma unroll
      for (int e = 0; e < 8; ++e) {
        float hf = bf2f((unsigned short)hv[e]);
        int u = usec * 32 + c8 * 8 + e;
        s0 += hf * wdl[u][0];
        s1 += hf * wdl[u][1];
      }
    }
    ypart[prow][0][usec] = s0;
    ypart[prow][1][usec] = s1;
    __syncthreads();
    if (tid < 32) {
      int b = tid >> 1, oc = tid & 1;
      float s = bd[oc0 + oc];
#pragma unroll
      for (int q = 0; q < 16; ++q) s += ypart[b][oc][q];
      out[((size_t)(b_base + b) * Tt + (Tt - 1)) * Oo + oc0 + oc] = s;
    }
  }
}

extern "C" void kernel_launch(void* const* d_in, const int* in_sizes, int n_in,
                              void* d_out, int out_size, void* d_ws, size_t ws_size,
                              hipStream_t stream) {
  const float* x  = (const float*)d_in[0];
  const float* Wx = (const float*)d_in[1];
  const float* Wh = (const float*)d_in[2];
  const float* bs = (const float*)d_in[3];
  const float* Wd = (const float*)d_in[4];
  const float* bd = (const float*)d_in[5];
  float* out = (float*)d_out;

  unsigned short* hbuf = (unsigned short*)d_ws;                       // 2*256*512 bf16 = 512 KiB
  unsigned* bar = (unsigned*)((char*)d_ws + (size_t)2 * Bb * Uu * 2); // 16 groups * 32 flags

  rnn_init_bar<<<1, 512, 0, stream>>>(bar);
  rnn_lstm_kernel<<<dim3(512), dim3(256), 0, stream>>>(x, Wx, Wh, bs, Wd, bd, out, hbuf, bar);
}